// Round 16
// baseline (40.919 us; speedup 1.0000x reference)
//
#include <hip/hip_runtime.h>

// QueryAndGroup: ball_query(r=0.2, nsample=32) + group xyz (centered) + group features.
// B=4, N=16384, M=2048, C=64. Output (B, 67, M, 32) f32.
//
// Ladder: R13 fused WPB=2 = 34.66us best; all splits regressed (fused
// scan||gather overlap is the real load balancer). This round: block-coop
// STAGED scan -- 4 waves/block share each 256-pt xyz4 group via double-buffered
// LDS (4KB/buf): global scan traffic & VMEM issue /4 (waves previously loaded
// identical data), next-group load issued before consuming current (latency
// under compute), exit via __syncthreads_and. Gather unchanged from R13
// (row preload, nt output stores, XCD-batch swizzle).

typedef float vf4 __attribute__((ext_vector_type(4)));

constexpr int Bc = 4, Nc = 16384, Mc = 2048, Cc = 64, Sc = 32;
constexpr int NQ = Bc * Mc;          // 8192 queries

// grid (Nc/64, Bc+1): y<Bc = transpose roles; y==Bc = xyz4 pack role.
__global__ __launch_bounds__(256) void prep_kernel(
    const float* __restrict__ feat,  // (B, C, N)
    const float* __restrict__ xyz,   // (B, N, 3)
    float* __restrict__ featT,       // (B, N, C)
    vf4* __restrict__ xyz4)          // (B*N) packed {x,y,z,0}
{
    if (blockIdx.y == Bc) {
        const int t = blockIdx.x * 256 + threadIdx.x;
        const float* p = xyz + (size_t)t * 3;
        vf4 v; v.x = p[0]; v.y = p[1]; v.z = p[2]; v.w = 0.0f;
        xyz4[t] = v;
        return;
    }
    __shared__ float tile[64][65];
    const int b = blockIdx.y;
    const int nbase = blockIdx.x * 64;
    const int tn = threadIdx.x & 63;
    const int tq = threadIdx.x >> 6;  // 0..3
    const float* fb = feat + (size_t)b * Cc * Nc;
    float* ob = featT + (size_t)b * Nc * Cc;
    #pragma unroll
    for (int k = 0; k < 16; ++k) {
        const int c = k * 4 + tq;
        tile[tn][c] = fb[(size_t)c * Nc + nbase + tn];      // coalesced reads
    }
    __syncthreads();
    #pragma unroll
    for (int k = 0; k < 16; ++k) {
        const int nl = k * 4 + tq;
        ob[(size_t)(nbase + nl) * Cc + tn] = tile[nl][tn];  // coalesced writes
    }
}

__global__ __launch_bounds__(256) void qg_kernel(
    const vf4* __restrict__ xyz4,       // (B*N) packed
    const float* __restrict__ new_xyz,  // (B, M, 3)
    const float* __restrict__ featT,    // (B, N, C)
    float* __restrict__ out)            // (B, 67, M, 32)
{
#pragma clang fp contract(off)
    const int t    = threadIdx.x;
    const int lane = t & 63;
    const int wv   = t >> 6;

    // XCD-batch swizzle: all 4 waves of a block on the same batch.
    const int xcd = blockIdx.x & 7;
    const int b   = xcd >> 1;
    const int m   = ((xcd & 1) << 10) + (blockIdx.x >> 3) * 4 + wv;

    __shared__ vf4 stage[2][256];     // double-buffered 256-pt groups (8 KB)
    __shared__ int sidx[4][Sc];

    const float r2 = 0.2f * 0.2f;
    const float* nz = new_xyz + (size_t)(b * Mc + m) * 3;
    const float qx = nz[0], qy = nz[1], qz = nz[2];
    const vf4* xb4 = xyz4 + (size_t)b * Nc;

    int count = 0, firstIdx = 0;      // wave-uniform
    const unsigned long long lt = (1ull << lane) - 1ull;

    // Prologue: stage group 0.
    stage[0][t] = xb4[t];
    __syncthreads();

    int p = 0;
    for (int base = 0; base < Nc; base += 256) {
        const int nb = base + 256;
        const bool have_next = (nb < Nc);
        vf4 nv;
        if (have_next) nv = xb4[nb + t];          // issue next-group load early

        if (count < Sc) {                          // wave-uniform predicate
            #pragma unroll
            for (int u = 0; u < 4; ++u) {
                const vf4 pt = stage[p][u * 64 + lane];
                const float dx = qx - pt.x, dy = qy - pt.y, dz = qz - pt.z;
                float d2 = dx * dx + dy * dy;      // no fma: match np/jax f32
                d2 = d2 + dz * dz;
                const bool in = d2 < r2;
                const unsigned long long mask = __ballot(in);
                if (in) {
                    const int slot = count + __popcll(mask & lt);
                    if (slot < Sc) sidx[wv][slot] = base + u * 64 + lane;
                }
                if (count == 0 && mask != 0ull)
                    firstIdx = base + u * 64 + __builtin_ctzll(mask);
                count += __popcll(mask);
            }
        }

        if (have_next) stage[p ^ 1][t] = nv;       // vmcnt wait lands here
        const int alldone = __syncthreads_and(count >= Sc);
        if (alldone || !have_next) break;
        p ^= 1;
    }
    {
        const int start = count < Sc ? count : Sc;
        if (start + lane < Sc) sidx[wv][start + lane] = firstIdx;
    }
    __syncthreads();   // sidx visibility (block already barrier-synced anyway)

    const int s     = lane & 31;
    const int chalf = lane >> 5;
    const int myid  = sidx[wv][s];
    float* ob = out + ((size_t)b * 67 * Mc + m) * Sc;

    // ---- PRELOAD: all 9 loads issued before any store (R13 verbatim) ----
    const float* ftb = featT + ((size_t)b * Nc + myid) * Cc;
    vf4 vr[8];
    #pragma unroll
    for (int it = 0; it < 8; ++it)
        vr[it] = *(const vf4*)(ftb + (it * 2 + chalf) * 4);
    const vf4 pp = xb4[myid];

    // Centered-xyz channels 0..2 (nt stores).
    if (chalf == 0) {
        __builtin_nontemporal_store(pp.x - qx, &ob[(size_t)0 * (Mc * Sc) + s]);
        __builtin_nontemporal_store(pp.z - qz, &ob[(size_t)2 * (Mc * Sc) + s]);
    } else {
        __builtin_nontemporal_store(pp.y - qy, &ob[(size_t)1 * (Mc * Sc) + s]);
    }

    // Feature stores: 32 s-coalesced 128B-segment nt stores.
    #pragma unroll
    for (int it = 0; it < 8; ++it) {
        const int c4 = it * 2 + chalf;                  // 0..15
        #pragma unroll
        for (int k = 0; k < 4; ++k)
            __builtin_nontemporal_store(
                vr[it][k], &ob[(size_t)(3 + c4 * 4 + k) * (Mc * Sc) + s]);
    }
}

// Fallback if ws too small: fused kernel with direct (C,N) gather (same values).
__global__ __launch_bounds__(256) void qg_fallback_kernel(
    const float* __restrict__ xyz, const float* __restrict__ new_xyz,
    const float* __restrict__ feat, float* __restrict__ out)
{
#pragma clang fp contract(off)
    const int lane = threadIdx.x & 63;
    const int wv   = threadIdx.x >> 6;
    const int q    = blockIdx.x * 4 + wv;
    const int b    = q >> 11;
    const int m    = q & (Mc - 1);
    __shared__ int sidx[4][Sc];
    const float r2 = 0.2f * 0.2f;
    const float* nz = new_xyz + (size_t)(b * Mc + m) * 3;
    const float qx = nz[0], qy = nz[1], qz = nz[2];
    const float* xb = xyz + (size_t)b * Nc * 3;
    int count = 0, firstIdx = 0;
    const unsigned long long lt = (1ull << lane) - 1ull;
    for (int base = 0; base < Nc; base += 64) {
        const int i = base + lane;
        const float px = xb[i * 3], py = xb[i * 3 + 1], pz = xb[i * 3 + 2];
        const float dx = qx - px, dy = qy - py, dz = qz - pz;
        float d2 = dx * dx + dy * dy; d2 = d2 + dz * dz;
        const bool in = d2 < r2;
        const unsigned long long mask = __ballot(in);
        if (in) {
            const int slot = count + __popcll(mask & lt);
            if (slot < Sc) sidx[wv][slot] = i;
        }
        if (count == 0 && mask != 0ull) firstIdx = base + __builtin_ctzll(mask);
        count += __popcll(mask);
        if (count >= Sc) break;
    }
    const int start = count < Sc ? count : Sc;
    if (start + lane < Sc) sidx[wv][start + lane] = firstIdx;
    asm volatile("s_waitcnt lgkmcnt(0)" ::: "memory");
    const int s = lane & 31, chalf = lane >> 5;
    const int myid = sidx[wv][s];
    float* ob = out + ((size_t)b * 67 * Mc + m) * Sc;
    ob[(size_t)chalf * (Mc * Sc) + s] = xb[(size_t)myid * 3 + chalf] - (chalf ? qy : qx);
    if (chalf == 0)
        ob[(size_t)2 * (Mc * Sc) + s] = xb[(size_t)myid * 3 + 2] - qz;
    const float* fb = feat + (size_t)b * Cc * Nc;
    #pragma unroll
    for (int it = 0; it < 32; ++it) {
        const int c = it * 2 + chalf;
        ob[(size_t)(3 + c) * (Mc * Sc) + s] = fb[(size_t)c * Nc + myid];
    }
}

extern "C" void kernel_launch(void* const* d_in, const int* in_sizes, int n_in,
                              void* d_out, int out_size, void* d_ws, size_t ws_size,
                              hipStream_t stream) {
    const float* xyz     = (const float*)d_in[0];
    const float* new_xyz = (const float*)d_in[1];
    const float* feat    = (const float*)d_in[2];
    float* out           = (float*)d_out;

    const size_t featT_bytes = (size_t)Bc * Nc * Cc * sizeof(float);  // 16.8 MB
    const size_t xyz4_bytes  = (size_t)Bc * Nc * sizeof(vf4);         //  1.0 MB

    if (ws_size >= featT_bytes + xyz4_bytes) {
        float* featT = (float*)d_ws;
        vf4*   xyz4  = (vf4*)((char*)d_ws + featT_bytes);
        hipLaunchKernelGGL(prep_kernel, dim3(Nc / 64, Bc + 1), dim3(256), 0, stream,
                           feat, xyz, featT, xyz4);
        hipLaunchKernelGGL(qg_kernel, dim3(NQ / 4), dim3(256), 0, stream,
                           xyz4, new_xyz, featT, out);
    } else {
        hipLaunchKernelGGL(qg_fallback_kernel, dim3(NQ / 4), dim3(256), 0, stream,
                           xyz, new_xyz, feat, out);
    }
}

// Round 17
// 34.941 us; speedup vs baseline: 1.1711x; 1.1711x over previous
//
#include <hip/hip_runtime.h>

// QueryAndGroup: ball_query(r=0.2, nsample=32) + group xyz (centered) + group features.
// B=4, N=16384, M=2048, C=64. Output (B, 67, M, 32) f32.
//
// Ladder: R13 (fused wave-per-query, WPB=2, preload, nt out stores, XCD
// swizzle) = 34.66us best. All cross-wave cooperation / splits regressed
// (7 attempts). This round, single variable: WPB 2 -> 1 -- single-wave
// workgroups (8192 x 64thr). Block retires when its own query finishes;
// zero sibling coupling; 1-wave workgroups need no barrier slot so 32 wg/CU
// sustains full occupancy (risk: wg dispatch limits -> R6-like regression;
// revert to R13 if so).

typedef float vf4 __attribute__((ext_vector_type(4)));

constexpr int Bc = 4, Nc = 16384, Mc = 2048, Cc = 64, Sc = 32;
constexpr int NQ = Bc * Mc;          // 8192 queries

// grid (Nc/64, Bc+1): y<Bc = transpose roles; y==Bc = xyz4 pack role.
__global__ __launch_bounds__(256) void prep_kernel(
    const float* __restrict__ feat,  // (B, C, N)
    const float* __restrict__ xyz,   // (B, N, 3)
    float* __restrict__ featT,       // (B, N, C)
    vf4* __restrict__ xyz4)          // (B*N) packed {x,y,z,0}
{
    if (blockIdx.y == Bc) {
        const int t = blockIdx.x * 256 + threadIdx.x;
        const float* p = xyz + (size_t)t * 3;
        vf4 v; v.x = p[0]; v.y = p[1]; v.z = p[2]; v.w = 0.0f;
        xyz4[t] = v;
        return;
    }
    __shared__ float tile[64][65];
    const int b = blockIdx.y;
    const int nbase = blockIdx.x * 64;
    const int tn = threadIdx.x & 63;
    const int tq = threadIdx.x >> 6;  // 0..3
    const float* fb = feat + (size_t)b * Cc * Nc;
    float* ob = featT + (size_t)b * Nc * Cc;
    #pragma unroll
    for (int k = 0; k < 16; ++k) {
        const int c = k * 4 + tq;
        tile[tn][c] = fb[(size_t)c * Nc + nbase + tn];      // coalesced reads
    }
    __syncthreads();
    #pragma unroll
    for (int k = 0; k < 16; ++k) {
        const int nl = k * 4 + tq;
        ob[(size_t)(nbase + nl) * Cc + tn] = tile[nl][tn];  // coalesced writes
    }
}

__global__ __launch_bounds__(64) void qg_kernel(
    const vf4* __restrict__ xyz4,       // (B*N) packed
    const float* __restrict__ new_xyz,  // (B, M, 3)
    const float* __restrict__ featT,    // (B, N, C)
    float* __restrict__ out)            // (B, 67, M, 32)
{
#pragma clang fp contract(off)
    const int lane = threadIdx.x;       // 64-thread block = one wave

    // XCD-batch swizzle: xcd = blockIdx%8 (dispatch round-robin), batch = xcd/2,
    // m = (xcd&1)*1024 + blockIdx/8. 8192 blocks: 1024/XCD, 2048/batch.
    const int xcd = blockIdx.x & 7;
    const int b   = xcd >> 1;
    const int m   = ((xcd & 1) << 10) + (blockIdx.x >> 3);

    __shared__ int sidx[Sc];

    const float r2 = 0.2f * 0.2f;
    const float* nz = new_xyz + (size_t)(b * Mc + m) * 3;
    const float qx = nz[0], qy = nz[1], qz = nz[2];
    const vf4* xb4 = xyz4 + (size_t)b * Nc;

    int count = 0, firstIdx = 0;
    const unsigned long long lt = (1ull << lane) - 1ull;

    // Double-buffered scan (unchanged).
    vf4 pv[4];
    #pragma unroll
    for (int u = 0; u < 4; ++u) pv[u] = xb4[u * 64 + lane];
    for (int base = 0; base < Nc; base += 256) {
        const int nb = (base + 256 < Nc) ? base + 256 : base;   // clamped prefetch
        vf4 nv[4];
        #pragma unroll
        for (int u = 0; u < 4; ++u) nv[u] = xb4[nb + u * 64 + lane];
        #pragma unroll
        for (int u = 0; u < 4; ++u) {
            const float dx = qx - pv[u].x, dy = qy - pv[u].y, dz = qz - pv[u].z;
            float d2 = dx * dx + dy * dy;   // no fma: match np/jax f32 rounding
            d2 = d2 + dz * dz;
            const bool in = d2 < r2;
            const unsigned long long mask = __ballot(in);
            if (in) {
                const int slot = count + __popcll(mask & lt);
                if (slot < Sc) sidx[slot] = base + u * 64 + lane;
            }
            if (count == 0 && mask != 0ull)
                firstIdx = base + u * 64 + __builtin_ctzll(mask);
            count += __popcll(mask);
        }
        if (count >= Sc) break;             // wave-uniform
        #pragma unroll
        for (int u = 0; u < 4; ++u) pv[u] = nv[u];
    }
    {
        const int start = count < Sc ? count : Sc;
        if (start + lane < Sc) sidx[start + lane] = firstIdx;
    }
    // Same-wave LDS visibility only.
    asm volatile("s_waitcnt lgkmcnt(0)" ::: "memory");

    const int s     = lane & 31;
    const int chalf = lane >> 5;
    const int myid  = sidx[s];
    float* ob = out + ((size_t)b * 67 * Mc + m) * Sc;

    // ---- PRELOAD: all 9 loads issued before any store ----
    const float* ftb = featT + ((size_t)b * Nc + myid) * Cc;
    vf4 vr[8];
    #pragma unroll
    for (int it = 0; it < 8; ++it)
        vr[it] = *(const vf4*)(ftb + (it * 2 + chalf) * 4);
    const vf4 p = xb4[myid];

    // Centered-xyz channels 0..2 (nt stores: no L2 allocate on the out stream).
    if (chalf == 0) {
        __builtin_nontemporal_store(p.x - qx, &ob[(size_t)0 * (Mc * Sc) + s]);
        __builtin_nontemporal_store(p.z - qz, &ob[(size_t)2 * (Mc * Sc) + s]);
    } else {
        __builtin_nontemporal_store(p.y - qy, &ob[(size_t)1 * (Mc * Sc) + s]);
    }

    // Feature stores: 32 s-coalesced 128B-segment nt stores.
    #pragma unroll
    for (int it = 0; it < 8; ++it) {
        const int c4 = it * 2 + chalf;                  // 0..15
        #pragma unroll
        for (int k = 0; k < 4; ++k)
            __builtin_nontemporal_store(
                vr[it][k], &ob[(size_t)(3 + c4 * 4 + k) * (Mc * Sc) + s]);
    }
}

// Fallback if ws too small: fused kernel with direct (C,N) gather (same values).
__global__ __launch_bounds__(256) void qg_fallback_kernel(
    const float* __restrict__ xyz, const float* __restrict__ new_xyz,
    const float* __restrict__ feat, float* __restrict__ out)
{
#pragma clang fp contract(off)
    const int lane = threadIdx.x & 63;
    const int wv   = threadIdx.x >> 6;
    const int q    = blockIdx.x * 4 + wv;
    const int b    = q >> 11;
    const int m    = q & (Mc - 1);
    __shared__ int sidx[4][Sc];
    const float r2 = 0.2f * 0.2f;
    const float* nz = new_xyz + (size_t)(b * Mc + m) * 3;
    const float qx = nz[0], qy = nz[1], qz = nz[2];
    const float* xb = xyz + (size_t)b * Nc * 3;
    int count = 0, firstIdx = 0;
    const unsigned long long lt = (1ull << lane) - 1ull;
    for (int base = 0; base < Nc; base += 64) {
        const int i = base + lane;
        const float px = xb[i * 3], py = xb[i * 3 + 1], pz = xb[i * 3 + 2];
        const float dx = qx - px, dy = qy - py, dz = qz - pz;
        float d2 = dx * dx + dy * dy; d2 = d2 + dz * dz;
        const bool in = d2 < r2;
        const unsigned long long mask = __ballot(in);
        if (in) {
            const int slot = count + __popcll(mask & lt);
            if (slot < Sc) sidx[wv][slot] = i;
        }
        if (count == 0 && mask != 0ull) firstIdx = base + __builtin_ctzll(mask);
        count += __popcll(mask);
        if (count >= Sc) break;
    }
    const int start = count < Sc ? count : Sc;
    if (start + lane < Sc) sidx[wv][start + lane] = firstIdx;
    asm volatile("s_waitcnt lgkmcnt(0)" ::: "memory");
    const int s = lane & 31, chalf = lane >> 5;
    const int myid = sidx[wv][s];
    float* ob = out + ((size_t)b * 67 * Mc + m) * Sc;
    ob[(size_t)chalf * (Mc * Sc) + s] = xb[(size_t)myid * 3 + chalf] - (chalf ? qy : qx);
    if (chalf == 0)
        ob[(size_t)2 * (Mc * Sc) + s] = xb[(size_t)myid * 3 + 2] - qz;
    const float* fb = feat + (size_t)b * Cc * Nc;
    #pragma unroll
    for (int it = 0; it < 32; ++it) {
        const int c = it * 2 + chalf;
        ob[(size_t)(3 + c) * (Mc * Sc) + s] = fb[(size_t)c * Nc + myid];
    }
}

extern "C" void kernel_launch(void* const* d_in, const int* in_sizes, int n_in,
                              void* d_out, int out_size, void* d_ws, size_t ws_size,
                              hipStream_t stream) {
    const float* xyz     = (const float*)d_in[0];
    const float* new_xyz = (const float*)d_in[1];
    const float* feat    = (const float*)d_in[2];
    float* out           = (float*)d_out;

    const size_t featT_bytes = (size_t)Bc * Nc * Cc * sizeof(float);  // 16.8 MB
    const size_t xyz4_bytes  = (size_t)Bc * Nc * sizeof(vf4);         //  1.0 MB

    if (ws_size >= featT_bytes + xyz4_bytes) {
        float* featT = (float*)d_ws;
        vf4*   xyz4  = (vf4*)((char*)d_ws + featT_bytes);
        hipLaunchKernelGGL(prep_kernel, dim3(Nc / 64, Bc + 1), dim3(256), 0, stream,
                           feat, xyz, featT, xyz4);
        hipLaunchKernelGGL(qg_kernel, dim3(NQ), dim3(64), 0, stream,
                           xyz4, new_xyz, featT, out);
    } else {
        hipLaunchKernelGGL(qg_fallback_kernel, dim3(NQ / 4), dim3(256), 0, stream,
                           xyz, new_xyz, feat, out);
    }
}

// Round 18
// 33.499 us; speedup vs baseline: 1.2215x; 1.0430x over previous
//
#include <hip/hip_runtime.h>

// QueryAndGroup: ball_query(r=0.2, nsample=32) + group xyz (centered) + group features.
// B=4, N=16384, M=2048, C=64. Output (B, 67, M, 32) f32.
//
// Ladder: R13 (fused wave-per-query, WPB=2, row preload, nt out stores, XCD
// swizzle) = 34.66us best; WPB=1 neutral (34.94); all coop/split variants
// regressed. This round: FLOAT4 STORES in the gather. Each lane owns a
// (channel-quad cq, sample-quad sq) 4x4 block: 4 vf4 row loads (same bytes,
// 128B-contiguous segments) + free in-register 4x4 transpose + 4 float4 nt
// stores per half (8 total). Per-lane gather VMEM: 8 loads + 8 stores (vs
// 8 + 32 scalar). Store instructions 4x down, 1KB/wave-instruction.
// xyz channels 0..2 keep the old scalar path (3 stores, 96 floats total).

typedef float vf4 __attribute__((ext_vector_type(4)));

#define WPB 2
constexpr int Bc = 4, Nc = 16384, Mc = 2048, Cc = 64, Sc = 32;
constexpr int NQ = Bc * Mc;          // 8192 queries

// grid (Nc/64, Bc+1): y<Bc = transpose roles; y==Bc = xyz4 pack role.
__global__ __launch_bounds__(256) void prep_kernel(
    const float* __restrict__ feat,  // (B, C, N)
    const float* __restrict__ xyz,   // (B, N, 3)
    float* __restrict__ featT,       // (B, N, C)
    vf4* __restrict__ xyz4)          // (B*N) packed {x,y,z,0}
{
    if (blockIdx.y == Bc) {
        const int t = blockIdx.x * 256 + threadIdx.x;
        const float* p = xyz + (size_t)t * 3;
        vf4 v; v.x = p[0]; v.y = p[1]; v.z = p[2]; v.w = 0.0f;
        xyz4[t] = v;
        return;
    }
    __shared__ float tile[64][65];
    const int b = blockIdx.y;
    const int nbase = blockIdx.x * 64;
    const int tn = threadIdx.x & 63;
    const int tq = threadIdx.x >> 6;  // 0..3
    const float* fb = feat + (size_t)b * Cc * Nc;
    float* ob = featT + (size_t)b * Nc * Cc;
    #pragma unroll
    for (int k = 0; k < 16; ++k) {
        const int c = k * 4 + tq;
        tile[tn][c] = fb[(size_t)c * Nc + nbase + tn];      // coalesced reads
    }
    __syncthreads();
    #pragma unroll
    for (int k = 0; k < 16; ++k) {
        const int nl = k * 4 + tq;
        ob[(size_t)(nbase + nl) * Cc + tn] = tile[nl][tn];  // coalesced writes
    }
}

__global__ __launch_bounds__(128) void qg_kernel(
    const vf4* __restrict__ xyz4,       // (B*N) packed
    const float* __restrict__ new_xyz,  // (B, M, 3)
    const float* __restrict__ featT,    // (B, N, C)
    float* __restrict__ out)            // (B, 67, M, 32)
{
#pragma clang fp contract(off)
    const int lane = threadIdx.x & 63;
    const int wv   = threadIdx.x >> 6;

    // XCD-batch swizzle: batch b on XCDs {2b,2b+1}.
    const int xcd = blockIdx.x & 7;
    const int b   = xcd >> 1;
    const int m   = ((xcd & 1) << 10) + (blockIdx.x >> 3) * WPB + wv;

    __shared__ int sidx[WPB][Sc];

    const float r2 = 0.2f * 0.2f;
    const float* nz = new_xyz + (size_t)(b * Mc + m) * 3;
    const float qx = nz[0], qy = nz[1], qz = nz[2];
    const vf4* xb4 = xyz4 + (size_t)b * Nc;

    int count = 0, firstIdx = 0;
    const unsigned long long lt = (1ull << lane) - 1ull;

    // Double-buffered scan (R13 verbatim).
    vf4 pv[4];
    #pragma unroll
    for (int u = 0; u < 4; ++u) pv[u] = xb4[u * 64 + lane];
    for (int base = 0; base < Nc; base += 256) {
        const int nb = (base + 256 < Nc) ? base + 256 : base;   // clamped prefetch
        vf4 nv[4];
        #pragma unroll
        for (int u = 0; u < 4; ++u) nv[u] = xb4[nb + u * 64 + lane];
        #pragma unroll
        for (int u = 0; u < 4; ++u) {
            const float dx = qx - pv[u].x, dy = qy - pv[u].y, dz = qz - pv[u].z;
            float d2 = dx * dx + dy * dy;   // no fma: match np/jax f32 rounding
            d2 = d2 + dz * dz;
            const bool in = d2 < r2;
            const unsigned long long mask = __ballot(in);
            if (in) {
                const int slot = count + __popcll(mask & lt);
                if (slot < Sc) sidx[wv][slot] = base + u * 64 + lane;
            }
            if (count == 0 && mask != 0ull)
                firstIdx = base + u * 64 + __builtin_ctzll(mask);
            count += __popcll(mask);
        }
        if (count >= Sc) break;             // wave-uniform
        #pragma unroll
        for (int u = 0; u < 4; ++u) pv[u] = nv[u];
    }
    {
        const int start = count < Sc ? count : Sc;
        if (start + lane < Sc) sidx[wv][start + lane] = firstIdx;
    }
    // Same-wave LDS visibility only; waves stay decoupled (no block barrier).
    asm volatile("s_waitcnt lgkmcnt(0)" ::: "memory");

    float* ob = out + ((size_t)b * 67 * Mc + m) * Sc;

    // ---- xyz channels 0..2 (old path: 96 floats/query) ----
    {
        const int s     = lane & 31;
        const int chalf = lane >> 5;
        const int myid  = sidx[wv][s];
        const vf4 p = xb4[myid];
        if (chalf == 0) {
            __builtin_nontemporal_store(p.x - qx, &ob[(size_t)0 * (Mc * Sc) + s]);
            __builtin_nontemporal_store(p.z - qz, &ob[(size_t)2 * (Mc * Sc) + s]);
        } else {
            __builtin_nontemporal_store(p.y - qy, &ob[(size_t)1 * (Mc * Sc) + s]);
        }
    }

    // ---- features: 4x4-block ownership, float4 loads AND stores ----
    // lane = (sq<<3) | cqlo: cqlo in 0..7 (low bits -> 128B-contiguous row
    // loads), sq in 0..7 (sample quad). Iter i: cq = cqlo + 8i (channel quad).
    const int cqlo = lane & 7;
    const int sq   = lane >> 3;
    int id4[4];
    #pragma unroll
    for (int k = 0; k < 4; ++k) id4[k] = sidx[wv][4 * sq + k];
    const float* fbase = featT + (size_t)b * Nc * Cc;

    #pragma unroll
    for (int i = 0; i < 2; ++i) {
        const int cq = cqlo + 8 * i;                 // 0..15
        vf4 v[4];
        #pragma unroll
        for (int k = 0; k < 4; ++k)                  // 4 rows, same channel-quad
            v[k] = *(const vf4*)(fbase + (size_t)id4[k] * Cc + 4 * cq);
        #pragma unroll
        for (int j = 0; j < 4; ++j) {                // in-register 4x4 transpose
            vf4 w;
            w.x = v[0][j]; w.y = v[1][j]; w.z = v[2][j]; w.w = v[3][j];
            __builtin_nontemporal_store(
                w, (vf4*)&ob[(size_t)(3 + 4 * cq + j) * (Mc * Sc) + 4 * sq]);
        }
    }
}

// Fallback if ws too small: fused kernel with direct (C,N) gather (same values).
__global__ __launch_bounds__(256) void qg_fallback_kernel(
    const float* __restrict__ xyz, const float* __restrict__ new_xyz,
    const float* __restrict__ feat, float* __restrict__ out)
{
#pragma clang fp contract(off)
    const int lane = threadIdx.x & 63;
    const int wv   = threadIdx.x >> 6;
    const int q    = blockIdx.x * 4 + wv;
    const int b    = q >> 11;
    const int m    = q & (Mc - 1);
    __shared__ int sidx[4][Sc];
    const float r2 = 0.2f * 0.2f;
    const float* nz = new_xyz + (size_t)(b * Mc + m) * 3;
    const float qx = nz[0], qy = nz[1], qz = nz[2];
    const float* xb = xyz + (size_t)b * Nc * 3;
    int count = 0, firstIdx = 0;
    const unsigned long long lt = (1ull << lane) - 1ull;
    for (int base = 0; base < Nc; base += 64) {
        const int i = base + lane;
        const float px = xb[i * 3], py = xb[i * 3 + 1], pz = xb[i * 3 + 2];
        const float dx = qx - px, dy = qy - py, dz = qz - pz;
        float d2 = dx * dx + dy * dy; d2 = d2 + dz * dz;
        const bool in = d2 < r2;
        const unsigned long long mask = __ballot(in);
        if (in) {
            const int slot = count + __popcll(mask & lt);
            if (slot < Sc) sidx[wv][slot] = i;
        }
        if (count == 0 && mask != 0ull) firstIdx = base + __builtin_ctzll(mask);
        count += __popcll(mask);
        if (count >= Sc) break;
    }
    const int start = count < Sc ? count : Sc;
    if (start + lane < Sc) sidx[wv][start + lane] = firstIdx;
    asm volatile("s_waitcnt lgkmcnt(0)" ::: "memory");
    const int s = lane & 31, chalf = lane >> 5;
    const int myid = sidx[wv][s];
    float* ob = out + ((size_t)b * 67 * Mc + m) * Sc;
    ob[(size_t)chalf * (Mc * Sc) + s] = xb[(size_t)myid * 3 + chalf] - (chalf ? qy : qx);
    if (chalf == 0)
        ob[(size_t)2 * (Mc * Sc) + s] = xb[(size_t)myid * 3 + 2] - qz;
    const float* fb = feat + (size_t)b * Cc * Nc;
    #pragma unroll
    for (int it = 0; it < 32; ++it) {
        const int c = it * 2 + chalf;
        ob[(size_t)(3 + c) * (Mc * Sc) + s] = fb[(size_t)c * Nc + myid];
    }
}

extern "C" void kernel_launch(void* const* d_in, const int* in_sizes, int n_in,
                              void* d_out, int out_size, void* d_ws, size_t ws_size,
                              hipStream_t stream) {
    const float* xyz     = (const float*)d_in[0];
    const float* new_xyz = (const float*)d_in[1];
    const float* feat    = (const float*)d_in[2];
    float* out           = (float*)d_out;

    const size_t featT_bytes = (size_t)Bc * Nc * Cc * sizeof(float);  // 16.8 MB
    const size_t xyz4_bytes  = (size_t)Bc * Nc * sizeof(vf4);         //  1.0 MB

    if (ws_size >= featT_bytes + xyz4_bytes) {
        float* featT = (float*)d_ws;
        vf4*   xyz4  = (vf4*)((char*)d_ws + featT_bytes);
        hipLaunchKernelGGL(prep_kernel, dim3(Nc / 64, Bc + 1), dim3(256), 0, stream,
                           feat, xyz, featT, xyz4);
        hipLaunchKernelGGL(qg_kernel, dim3(NQ / WPB), dim3(128), 0, stream,
                           xyz4, new_xyz, featT, out);
    } else {
        hipLaunchKernelGGL(qg_fallback_kernel, dim3(NQ / 4), dim3(256), 0, stream,
                           xyz, new_xyz, feat, out);
    }
}

// Round 19
// 33.296 us; speedup vs baseline: 1.2290x; 1.0061x over previous
//
#include <hip/hip_runtime.h>

// QueryAndGroup: ball_query(r=0.2, nsample=32) + group xyz (centered) + group features.
// B=4, N=16384, M=2048, C=64. Output (B, 67, M, 32) f32.
//
// Ladder: R17 = 33.5us (fused wave-per-query WPB=2, row preload, 4x4-block
// float4 gather stores, nt out, consumer XCD swizzle). This round: PRODUCER
// XCD alignment -- prep flattened to a 1D grid with the same blockIdx%8->XCD
// mapping as qg, so batch b's featT (4.2MB) and xyz4 (1MB) slices are written
// (and L2-cached) on XCDs {2b,2b+1} -- exactly where qg reads them. Converts
// ~75% of featT-row reads (67MB) and scan xyz4 reads (~200MB) from L3 (~450cy)
// to XCD-local L2 (~200cy). Mapping is bijective: if the %8 dispatch heuristic
// is wrong this is neutral, never incorrect.

typedef float vf4 __attribute__((ext_vector_type(4)));

#define WPB 2
constexpr int Bc = 4, Nc = 16384, Mc = 2048, Cc = 64, Sc = 32;
constexpr int NQ = Bc * Mc;          // 8192 queries

// 1D grid of 1280 blocks: [0,1024) transpose, [1024,1280) xyz4 pack.
// Both roles: xcd = blockIdx%8, batch = xcd/2 (matches qg's consumer swizzle).
__global__ __launch_bounds__(256) void prep_kernel(
    const float* __restrict__ feat,  // (B, C, N)
    const float* __restrict__ xyz,   // (B, N, 3)
    float* __restrict__ featT,       // (B, N, C)
    vf4* __restrict__ xyz4)          // (B*N) packed {x,y,z,0}
{
    const int i   = blockIdx.x;
    const int xcd = i & 7;
    const int b   = xcd >> 1;

    if (i >= 1024) {
        // pack role: 256 blocks; per batch 64 blocks (32 per XCD of its pair).
        const int j    = (i - 1024) >> 3;              // 0..31
        const int idxb = ((xcd & 1) << 5) + j;         // 0..63 within batch
        const int t    = idxb * 256 + threadIdx.x;     // 0..16383 within batch
        const float* p = xyz + ((size_t)b * Nc + t) * 3;
        vf4 v; v.x = p[0]; v.y = p[1]; v.z = p[2]; v.w = 0.0f;
        xyz4[(size_t)b * Nc + t] = v;
        return;
    }

    // transpose role: 1024 blocks; per batch 256 tiles (128 per XCD of pair).
    __shared__ float tile[64][65];
    const int nbase = ((((xcd & 1) << 7) + (i >> 3)) << 6);  // tile row base
    const int tn = threadIdx.x & 63;
    const int tq = threadIdx.x >> 6;  // 0..3
    const float* fb = feat + (size_t)b * Cc * Nc;
    float* ob = featT + (size_t)b * Nc * Cc;
    #pragma unroll
    for (int k = 0; k < 16; ++k) {
        const int c = k * 4 + tq;
        tile[tn][c] = fb[(size_t)c * Nc + nbase + tn];      // coalesced reads
    }
    __syncthreads();
    #pragma unroll
    for (int k = 0; k < 16; ++k) {
        const int nl = k * 4 + tq;
        ob[(size_t)(nbase + nl) * Cc + tn] = tile[nl][tn];  // coalesced writes
    }
}

__global__ __launch_bounds__(128) void qg_kernel(
    const vf4* __restrict__ xyz4,       // (B*N) packed
    const float* __restrict__ new_xyz,  // (B, M, 3)
    const float* __restrict__ featT,    // (B, N, C)
    float* __restrict__ out)            // (B, 67, M, 32)
{
#pragma clang fp contract(off)
    const int lane = threadIdx.x & 63;
    const int wv   = threadIdx.x >> 6;

    // Consumer XCD swizzle: batch b on XCDs {2b,2b+1}.
    const int xcd = blockIdx.x & 7;
    const int b   = xcd >> 1;
    const int m   = ((xcd & 1) << 10) + (blockIdx.x >> 3) * WPB + wv;

    __shared__ int sidx[WPB][Sc];

    const float r2 = 0.2f * 0.2f;
    const float* nz = new_xyz + (size_t)(b * Mc + m) * 3;
    const float qx = nz[0], qy = nz[1], qz = nz[2];
    const vf4* xb4 = xyz4 + (size_t)b * Nc;

    int count = 0, firstIdx = 0;
    const unsigned long long lt = (1ull << lane) - 1ull;

    // Double-buffered scan (R13 verbatim).
    vf4 pv[4];
    #pragma unroll
    for (int u = 0; u < 4; ++u) pv[u] = xb4[u * 64 + lane];
    for (int base = 0; base < Nc; base += 256) {
        const int nb = (base + 256 < Nc) ? base + 256 : base;   // clamped prefetch
        vf4 nv[4];
        #pragma unroll
        for (int u = 0; u < 4; ++u) nv[u] = xb4[nb + u * 64 + lane];
        #pragma unroll
        for (int u = 0; u < 4; ++u) {
            const float dx = qx - pv[u].x, dy = qy - pv[u].y, dz = qz - pv[u].z;
            float d2 = dx * dx + dy * dy;   // no fma: match np/jax f32 rounding
            d2 = d2 + dz * dz;
            const bool in = d2 < r2;
            const unsigned long long mask = __ballot(in);
            if (in) {
                const int slot = count + __popcll(mask & lt);
                if (slot < Sc) sidx[wv][slot] = base + u * 64 + lane;
            }
            if (count == 0 && mask != 0ull)
                firstIdx = base + u * 64 + __builtin_ctzll(mask);
            count += __popcll(mask);
        }
        if (count >= Sc) break;             // wave-uniform
        #pragma unroll
        for (int u = 0; u < 4; ++u) pv[u] = nv[u];
    }
    {
        const int start = count < Sc ? count : Sc;
        if (start + lane < Sc) sidx[wv][start + lane] = firstIdx;
    }
    // Same-wave LDS visibility only; waves stay decoupled (no block barrier).
    asm volatile("s_waitcnt lgkmcnt(0)" ::: "memory");

    float* ob = out + ((size_t)b * 67 * Mc + m) * Sc;

    // ---- xyz channels 0..2 ----
    {
        const int s     = lane & 31;
        const int chalf = lane >> 5;
        const int myid  = sidx[wv][s];
        const vf4 p = xb4[myid];
        if (chalf == 0) {
            __builtin_nontemporal_store(p.x - qx, &ob[(size_t)0 * (Mc * Sc) + s]);
            __builtin_nontemporal_store(p.z - qz, &ob[(size_t)2 * (Mc * Sc) + s]);
        } else {
            __builtin_nontemporal_store(p.y - qy, &ob[(size_t)1 * (Mc * Sc) + s]);
        }
    }

    // ---- features: 4x4-block ownership, float4 loads AND stores (R17) ----
    const int cqlo = lane & 7;
    const int sq   = lane >> 3;
    int id4[4];
    #pragma unroll
    for (int k = 0; k < 4; ++k) id4[k] = sidx[wv][4 * sq + k];
    const float* fbase = featT + (size_t)b * Nc * Cc;

    #pragma unroll
    for (int i = 0; i < 2; ++i) {
        const int cq = cqlo + 8 * i;                 // 0..15
        vf4 v[4];
        #pragma unroll
        for (int k = 0; k < 4; ++k)                  // 4 rows, same channel-quad
            v[k] = *(const vf4*)(fbase + (size_t)id4[k] * Cc + 4 * cq);
        #pragma unroll
        for (int j = 0; j < 4; ++j) {                // in-register 4x4 transpose
            vf4 w;
            w.x = v[0][j]; w.y = v[1][j]; w.z = v[2][j]; w.w = v[3][j];
            __builtin_nontemporal_store(
                w, (vf4*)&ob[(size_t)(3 + 4 * cq + j) * (Mc * Sc) + 4 * sq]);
        }
    }
}

// Fallback if ws too small: fused kernel with direct (C,N) gather (same values).
__global__ __launch_bounds__(256) void qg_fallback_kernel(
    const float* __restrict__ xyz, const float* __restrict__ new_xyz,
    const float* __restrict__ feat, float* __restrict__ out)
{
#pragma clang fp contract(off)
    const int lane = threadIdx.x & 63;
    const int wv   = threadIdx.x >> 6;
    const int q    = blockIdx.x * 4 + wv;
    const int b    = q >> 11;
    const int m    = q & (Mc - 1);
    __shared__ int sidx[4][Sc];
    const float r2 = 0.2f * 0.2f;
    const float* nz = new_xyz + (size_t)(b * Mc + m) * 3;
    const float qx = nz[0], qy = nz[1], qz = nz[2];
    const float* xb = xyz + (size_t)b * Nc * 3;
    int count = 0, firstIdx = 0;
    const unsigned long long lt = (1ull << lane) - 1ull;
    for (int base = 0; base < Nc; base += 64) {
        const int i = base + lane;
        const float px = xb[i * 3], py = xb[i * 3 + 1], pz = xb[i * 3 + 2];
        const float dx = qx - px, dy = qy - py, dz = qz - pz;
        float d2 = dx * dx + dy * dy; d2 = d2 + dz * dz;
        const bool in = d2 < r2;
        const unsigned long long mask = __ballot(in);
        if (in) {
            const int slot = count + __popcll(mask & lt);
            if (slot < Sc) sidx[wv][slot] = i;
        }
        if (count == 0 && mask != 0ull) firstIdx = base + __builtin_ctzll(mask);
        count += __popcll(mask);
        if (count >= Sc) break;
    }
    const int start = count < Sc ? count : Sc;
    if (start + lane < Sc) sidx[wv][start + lane] = firstIdx;
    asm volatile("s_waitcnt lgkmcnt(0)" ::: "memory");
    const int s = lane & 31, chalf = lane >> 5;
    const int myid = sidx[wv][s];
    float* ob = out + ((size_t)b * 67 * Mc + m) * Sc;
    ob[(size_t)chalf * (Mc * Sc) + s] = xb[(size_t)myid * 3 + chalf] - (chalf ? qy : qx);
    if (chalf == 0)
        ob[(size_t)2 * (Mc * Sc) + s] = xb[(size_t)myid * 3 + 2] - qz;
    const float* fb = feat + (size_t)b * Cc * Nc;
    #pragma unroll
    for (int it = 0; it < 32; ++it) {
        const int c = it * 2 + chalf;
        ob[(size_t)(3 + c) * (Mc * Sc) + s] = fb[(size_t)c * Nc + myid];
    }
}

extern "C" void kernel_launch(void* const* d_in, const int* in_sizes, int n_in,
                              void* d_out, int out_size, void* d_ws, size_t ws_size,
                              hipStream_t stream) {
    const float* xyz     = (const float*)d_in[0];
    const float* new_xyz = (const float*)d_in[1];
    const float* feat    = (const float*)d_in[2];
    float* out           = (float*)d_out;

    const size_t featT_bytes = (size_t)Bc * Nc * Cc * sizeof(float);  // 16.8 MB
    const size_t xyz4_bytes  = (size_t)Bc * Nc * sizeof(vf4);         //  1.0 MB

    if (ws_size >= featT_bytes + xyz4_bytes) {
        float* featT = (float*)d_ws;
        vf4*   xyz4  = (vf4*)((char*)d_ws + featT_bytes);
        hipLaunchKernelGGL(prep_kernel, dim3(1280), dim3(256), 0, stream,
                           feat, xyz, featT, xyz4);
        hipLaunchKernelGGL(qg_kernel, dim3(NQ / WPB), dim3(128), 0, stream,
                           xyz4, new_xyz, featT, out);
    } else {
        hipLaunchKernelGGL(qg_fallback_kernel, dim3(NQ / 4), dim3(256), 0, stream,
                           xyz, new_xyz, feat, out);
    }
}